// Round 3
// baseline (345.853 us; speedup 1.0000x reference)
//
#include <hip/hip_runtime.h>
#include <hip/hip_cooperative_groups.h>
#include <cstdint>

namespace cg = cooperative_groups;

#define NPX 2304      // 48*48
#define MM 6912       // 3*2304
#define NW 108        // MM/64
#define TOPK 2000
#define NEGV -1000000000.0f
#define OBJ_THRF 0.3f
#define IOU_THRF 0.7f
#define IMGF 768.0f
#define KSPLIT 8      // conv k-splits: 32 ic per split

typedef unsigned long long u64;
typedef unsigned int u32;

__device__ __forceinline__ u64 shfl64(u64 v, int src) {
  int lo = __shfl((int)(v & 0xffffffffull), src, 64);
  int hi = __shfl((int)(v >> 32), src, 64);
  return ((u64)(u32)hi << 32) | (u32)lo;
}

// ---------------- conv 3x3, 256->256: 3 px x 8 oc per thread ----------------
// grid (3 row-chunks, 32 oc-tiles, 8 k-splits) = 768 blocks, 256 thr.
// thread: row = br0 + tid/16, cols 3*(tid%16)..+2. Per ic: 15 x-LDS reads +
// 18 broadcast weight reads feed 216 FMAs (2.4x better amortization than r0).
// Bit-exact vs round-0: per-output accumulation order over (global ic asc,
// tap asc) with identical operand pairs.
__global__ __launch_bounds__(256) void k_conv(const float* __restrict__ x,
                                              const float* __restrict__ cw,
                                              float* __restrict__ part) {
  __shared__ float xs[8 * 18 * 52];   // 29,952 B
  __shared__ float wsh[32 * 9 * 8];   // 9,216 B   [r=ic*9+tap][oc]
  const int tid = threadIdx.x;
  const int ks = blockIdx.z;
  const int oc0 = blockIdx.y * 8;
  const int lr = tid >> 4;            // 0..15
  const int c0 = (tid & 15) * 3;      // 0,3,..,45
  const int br0 = blockIdx.x * 16;
  const int grow = br0 + lr;

  // stage this ksplit's weights straight from cw (k_wt eliminated):
  // cw[oc][ic*9+tap], contiguous 288-float run per oc for this ksplit.
  for (int e = tid; e < 2304; e += 256) {
    int k = e / 288, r = e - k * 288;
    wsh[r * 8 + k] = cw[(size_t)(oc0 + k) * 2304 + ks * 288 + r];
  }

  float acc[3][8];
#pragma unroll
  for (int p = 0; p < 3; ++p)
#pragma unroll
    for (int k = 0; k < 8; ++k) acc[p][k] = 0.f;

  for (int icc = 0; icc < 4; ++icc) {
    const int icg = ks * 32 + icc * 8;   // global first ic of this stage
    __syncthreads();                      // xs reuse guard (also covers wsh)
    for (int e = tid; e < 8 * 18 * 50; e += 256) {
      int ic = e / 900, rem = e - ic * 900;
      int r = rem / 50, cc = rem - r * 50 - 1;
      int gr = br0 - 1 + r;
      float v = 0.f;
      if (cc >= 0 && cc < 48 && gr >= 0 && gr < 48)
        v = x[(size_t)(icg + ic) * NPX + gr * 48 + cc];
      xs[(ic * 18 + r) * 52 + cc + 1] = v;
    }
    __syncthreads();
#pragma unroll 2
    for (int ic = 0; ic < 8; ++ic) {
      float xr[15];
#pragma unroll
      for (int dr = 0; dr < 3; ++dr)
#pragma unroll
        for (int j = 0; j < 5; ++j)
          xr[dr * 5 + j] = xs[(ic * 18 + lr + dr) * 52 + c0 + j];
      const int rb0 = (icc * 8 + ic) * 9;
#pragma unroll
      for (int t = 0; t < 9; ++t) {
        const int dr = t / 3, dc = t % 3;
        const float4 wa = *(const float4*)&wsh[(rb0 + t) * 8];
        const float4 wb = *(const float4*)&wsh[(rb0 + t) * 8 + 4];
#pragma unroll
        for (int p = 0; p < 3; ++p) {
          const float xv = xr[dr * 5 + p + dc];
          acc[p][0] += xv * wa.x;  acc[p][1] += xv * wa.y;
          acc[p][2] += xv * wa.z;  acc[p][3] += xv * wa.w;
          acc[p][4] += xv * wb.x;  acc[p][5] += xv * wb.y;
          acc[p][6] += xv * wb.z;  acc[p][7] += xv * wb.w;
        }
      }
    }
  }
  const int pxb = grow * 48 + c0;
#pragma unroll
  for (int k = 0; k < 8; ++k)
#pragma unroll
    for (int p = 0; p < 3; ++p)
      part[((size_t)ks * 256 + oc0 + k) * NPX + pxb + p] = acc[p][k];
}

// ---------------- merge-path step (device) ----------------
__device__ __forceinline__ void merge_step(const u64* __restrict__ in,
                                           u64* __restrict__ outk, int L, int i,
                                           int fin,
                                           const float* __restrict__ s,
                                           const float4* __restrict__ boxes,
                                           float* __restrict__ ssc,
                                           float4* __restrict__ sboxes) {
  const int pair = i / (2 * L);
  const int r = i - pair * 2 * L;
  const u64* A = in + (size_t)pair * 2 * L;
  const u64* B = A + L;
  int lo = (r > L) ? (r - L) : 0;
  int hi = (r < L) ? r : L;
  while (lo < hi) {
    int mid = (lo + hi) >> 1;
    if (A[mid] < B[r - 1 - mid]) lo = mid + 1; else hi = mid;
  }
  int a = lo, bi = r - lo;
  u64 av = (a < L) ? A[a] : ~0ull;
  u64 bv = (bi < L) ? B[bi] : ~0ull;
  u64 o = (av < bv) ? av : bv;
  outk[i] = o;
  if (fin && i < MM) {
    int idx = (int)(u32)o;
    ssc[i] = s[idx];
    sboxes[i] = boxes[idx];
  }
}

// ---------------- cooperative tail: dq + dfin + nz-zero + sort + merges ----
// 8 blocks x 1024 threads; phase code identical to round-2 kernels, only the
// thread->work mapping changes (per-output numerics untouched).
__global__ __launch_bounds__(1024) void k_tail(
    const float* __restrict__ part, const float* __restrict__ cb,
    const float* __restrict__ dw, const float* __restrict__ db,
    const float* __restrict__ rw, const float* __restrict__ rb,
    const float* __restrict__ anch,
    float* __restrict__ qacc, float* __restrict__ s, float4* __restrict__ boxes,
    u64* __restrict__ keysA, u64* __restrict__ keysB,
    float* __restrict__ ssc, float4* __restrict__ sboxes,
    u64* __restrict__ nz) {
  cg::grid_group grid = cg::this_grid();
  __shared__ float wl[256 * 16];   // 16 KB  [c][o], all 4 quarters
  __shared__ u64 lds[1024];        // 8 KB   sort buffer
  const int tid = threadIdx.x;
  const int bid = blockIdx.x;
  const int gtid = bid * 1024 + tid;      // 0..8191

  // ---- stage head weights ----
  for (int e = tid; e < 3840; e += 1024) {
    int o = e % 15, c = e / 15;
    wl[c * 16 + o] = (o < 3) ? dw[o * 256 + c] : rw[(o - 3) * 256 + c];
  }
  __syncthreads();

  // ---- dq phase: 144 (pxblk,cq) wave-tasks over 128 waves ----
  const int lane = tid & 63;
  for (int task = bid * 16 + (tid >> 6); task < 144; task += 128) {
    const int pxblk = task >> 2, cq = task & 3;
    const int px = pxblk * 64 + lane;
    float acc[15];
#pragma unroll
    for (int o = 0; o < 15; o++) acc[o] = 0.f;
#pragma unroll 4
    for (int ci = 0; ci < 64; ++ci) {
      int c = cq * 64 + ci;
      float v = cb[c];
#pragma unroll
      for (int kks = 0; kks < KSPLIT; ++kks)
        v += part[((size_t)kks * 256 + c) * NPX + px];
#pragma unroll
      for (int o = 0; o < 15; o++) acc[o] += v * wl[c * 16 + o];
    }
#pragma unroll
    for (int o = 0; o < 15; o++)
      qacc[((size_t)cq * NPX + px) * 16 + o] = acc[o];
  }
  grid.sync();

  // ---- dfin + nz zero (part is dead now; nz aliases part region) ----
  for (int i = gtid; i < MM * 2; i += 8192) nz[i] = 0;
  if (gtid < NPX) {
    const int p = gtid;
    float a[15];
#pragma unroll
    for (int o = 0; o < 15; o++)
      a[o] = qacc[((size_t)0 * NPX + p) * 16 + o] +
             qacc[((size_t)1 * NPX + p) * 16 + o] +
             qacc[((size_t)2 * NPX + p) * 16 + o] +
             qacc[((size_t)3 * NPX + p) * 16 + o];
    const float4* an4 = (const float4*)anch;
#pragma unroll
    for (int aa = 0; aa < 3; ++aa) {
      int m = aa * NPX + p;
      float logit = a[aa] + db[aa];
      float score = 1.f / (1.f + expf(-logit));
      float dxv = a[3 + 0 + aa] + rb[0 + aa];
      float dyv = a[3 + 3 + aa] + rb[3 + aa];
      float dwv = a[3 + 6 + aa] + rb[6 + aa];
      float dhv = a[3 + 9 + aa] + rb[9 + aa];
      float4 an = an4[m];
      float aw = an.z - an.x;
      float ah = an.w - an.y;
      float acx = an.y + aw * 0.5f;  // NOTE: intentionally swapped (reference quirk)
      float acy = an.x + ah * 0.5f;  // NOTE: intentionally swapped (reference quirk)
      float pxc = acx + dxv * aw;
      float pyc = acy + dyv * ah;
      float pw = aw * expf(dwv);
      float ph = ah * expf(dhv);
      float b0 = pxc - pw * 0.5f, b1 = pyc - ph * 0.5f;
      float b2 = pxc + pw * 0.5f, b3 = pyc + ph * 0.5f;
      b0 = fminf(fmaxf(b0, 0.f), IMGF);
      b1 = fminf(fmaxf(b1, 0.f), IMGF);
      b2 = fminf(fmaxf(b2, 0.f), IMGF);
      b3 = fminf(fmaxf(b3, 0.f), IMGF);
      float hts = b2 - b0, wds = b3 - b1;
      bool valid = (hts > 0.f) && (wds > 0.f) && (score > OBJ_THRF);
      s[m] = valid ? score : NEGV;
      boxes[m] = make_float4(b0, b1, b2, b3);
    }
  }
  grid.sync();

  // ---- bitonic sort: block bid sorts s[bid*1024 .. +1023] ----
  {
    int i = bid * 1024 + tid;
    u64 p;
    if (i < MM) {
      u32 u = __float_as_uint(s[i]);
      u = u ^ (u32)(((int)u >> 31) | 0x80000000);
      p = ((u64)(~u) << 32) | (u32)i;
    } else {
      p = ~0ull;
    }
    lds[tid] = p;
    for (u32 kk = 2; kk <= 1024; kk <<= 1) {
      for (u32 j = kk >> 1; j > 0; j >>= 1) {
        __syncthreads();
        if (tid < 512) {
          int ii = ((tid & ~(j - 1)) << 1) | (tid & (j - 1));
          int l = ii | j;
          bool up = ((ii & kk) == 0);
          u64 a = lds[ii], c = lds[l];
          u64 mn = a < c ? a : c;
          u64 mx = a < c ? c : a;
          lds[ii] = up ? mn : mx;
          lds[l] = up ? mx : mn;
        }
      }
    }
    __syncthreads();
    keysA[bid * 1024 + tid] = lds[tid];
  }
  grid.sync();

  // ---- merge-path rounds ----
  merge_step(keysA, keysB, 1024, gtid, 0, s, boxes, ssc, sboxes);
  grid.sync();
  merge_step(keysB, keysA, 2048, gtid, 0, s, boxes, ssc, sboxes);
  grid.sync();
  merge_step(keysA, keysB, 4096, gtid, 1, s, boxes, ssc, sboxes);
}

// ---------------- IOU suppression bit-matrix (transposed) ----------------
__global__ __launch_bounds__(256) void k_mask(const float4* __restrict__ sboxes,
                                              u64* __restrict__ mask_t,
                                              u64* __restrict__ nz) {
  __shared__ float4 rb_[64];
  const int rt = blockIdx.x;
  const int w = blockIdx.y * 4 + (threadIdx.x >> 6);
  const int lane = threadIdx.x & 63;
  if (threadIdx.x < 64) rb_[threadIdx.x] = sboxes[rt * 64 + threadIdx.x];
  __syncthreads();
  if (w < rt) return;
  float4 c = sboxes[w * 64 + lane];
  float areaC = (c.z - c.x) * (c.w - c.y);
  u64 myw = 0;
  for (int r = 0; r < 64; ++r) {
    float4 b = rb_[r];
    float iw = fmaxf(fminf(b.z, c.z) - fmaxf(b.x, c.x), 0.f);
    float ih = fmaxf(fminf(b.w, c.w) - fmaxf(b.y, c.y), 0.f);
    float inter = iw * ih;
    float areaB = (b.z - b.x) * (b.w - b.y);
    float un = fmaxf(areaB + areaC - inter, 1e-9f);
    bool bit = (inter / un) > IOU_THRF;
    u64 bal = __ballot(bit);
    if (lane == r) myw = bal;
  }
  mask_t[(size_t)w * MM + rt * 64 + lane] = myw;
  if (myw) atomicOr(&nz[(rt * 64 + lane) * 2 + (w >> 6)], 1ull << (w & 63));
}

// ---------------- serial NMS scan + output ----------------
__global__ __launch_bounds__(256) void k_scan(const u64* __restrict__ mask_t,
                                              const u64* __restrict__ nz,
                                              const float* __restrict__ ssc,
                                              const float4* __restrict__ sboxes,
                                              float* __restrict__ out) {
  __shared__ u64 remv[NW];
  __shared__ u64 keepw[NW];
  __shared__ int blist[64];
  __shared__ int nkS;
  __shared__ int kcntS;
  __shared__ int pref[NW];
  const int tid = threadIdx.x;
  if (tid < NW) { remv[tid] = 0; keepw[tid] = 0; }
  if (tid == 0) kcntS = 0;
  __syncthreads();

  for (int c = 0; c < NW; ++c) {
    if (tid < 64) {
      const int lane = tid;
      u64 dg = mask_t[(size_t)c * MM + c * 64 + lane];
      float sv = ssc[c * 64 + lane];
      u64 vb = __ballot(sv > OBJ_THRF);
      u64 w0 = remv[c];
      u64 cand = vb & ~w0;
      u64 above = (lane < 63) ? ~((2ull << lane) - 1ull) : 0ull;
      bool inC = ((cand >> lane) & 1ull) != 0;
      u64 conf = __ballot(inC && ((dg & above & cand) != 0ull));
      u64 kb;
      if (conf == 0ull) {
        kb = cand;
      } else {
        u64 w = w0;
        kb = 0;
        u64 rem = cand;
        while (rem) {
          int b = __ffsll(rem) - 1;
          kb |= (1ull << b);
          w |= shfl64(dg, b);
          rem = vb & ~w;
        }
      }
      int below = __popcll(kb & ((1ull << lane) - 1ull));
      if ((kb >> lane) & 1ull) blist[below] = lane;
      if (lane == 0) {
        keepw[c] = kb;
        nkS = __popcll(kb);
        kcntS += __popcll(kb);
      }
    }
    __syncthreads();
    int nk = nkS;
    if (tid < nk) {
      int row = c * 64 + blist[tid];
      u64 nz0 = nz[row * 2], nz1 = nz[row * 2 + 1];
      if (c < 64) {
        nz0 &= (c < 63) ? ~((2ull << c) - 1ull) : 0ull;
      } else {
        nz0 = 0;
        int cc = c - 64;
        nz1 &= ~((2ull << cc) - 1ull);
      }
      while (nz0) {
        int wv = __ffsll(nz0) - 1; nz0 &= nz0 - 1;
        atomicOr(&remv[wv], mask_t[(size_t)wv * MM + row]);
      }
      while (nz1) {
        int wv = __ffsll(nz1) - 1; nz1 &= nz1 - 1;
        atomicOr(&remv[wv + 64], mask_t[(size_t)(wv + 64) * MM + row]);
      }
    }
    __syncthreads();
    if (kcntS >= TOPK) break;
  }

  if (tid == 0) {
    int run = 0;
    for (int cc = 0; cc < NW; ++cc) { pref[cc] = run; run += __popcll(keepw[cc]); }
  }
  __syncthreads();
  for (int e = tid; e < TOPK * 5; e += 256) out[e] = (e < TOPK) ? -1.0f : 0.0f;
  __syncthreads();
  float4* ob = (float4*)(out + TOPK);
  for (int i = tid; i < MM; i += 256) {
    int cc = i >> 6, b = i & 63;
    u64 kb = keepw[cc];
    if ((kb >> b) & 1ull) {
      int rank = pref[cc] + __popcll(kb & ((1ull << b) - 1ull));
      if (rank < TOPK) {
        out[rank] = ssc[i];
        ob[rank] = sboxes[i];
      }
    }
  }
}

extern "C" void kernel_launch(void* const* d_in, const int* in_sizes, int n_in,
                              void* d_out, int out_size, void* d_ws, size_t ws_size,
                              hipStream_t stream) {
  const float* x  = (const float*)d_in[0];
  const float* cw = (const float*)d_in[1];
  const float* cb = (const float*)d_in[2];
  const float* dw = (const float*)d_in[3];
  const float* db = (const float*)d_in[4];
  const float* rw = (const float*)d_in[5];
  const float* rb = (const float*)d_in[6];
  const float* an = (const float*)d_in[7];
  char* ws = (char*)d_ws;
  // Time-phased aliasing of [0 .. 18.9MB):
  //   k_conv + k_tail(dq phase): part
  //   k_tail(dfin onward): keysA/B at [0..128KB), nz at 5,971,968
  //   k_mask,k_scan: mask at [0..5,971,968)
  float*  part   = (float*)(ws);                 // 18,874,368 B (KSPLIT*256*NPX*4)
  u64*    keysA  = (u64*)(ws);                   // 65,536 B
  u64*    keysB  = (u64*)(ws + 65536);           // 65,536 B
  u64*    mask   = (u64*)(ws);                   // 5,971,968 B
  u64*    nz     = (u64*)(ws + 5971968);         // 110,592 B
  float*  qacc   = (float*)(ws + 18874368);      // 589,824 B
  float*  s      = (float*)(ws + 21233664);      // 27,648 B
  float4* boxes  = (float4*)(ws + 21261312);     // 110,592 B
  float*  ssc    = (float*)(ws + 21371904);      // 27,648 B
  float4* sboxes = (float4*)(ws + 21399552);     // 110,592 B -> total 21,510,144 B
  float* out = (float*)d_out;

  hipLaunchKernelGGL(k_conv, dim3(3, 32, KSPLIT), dim3(256), 0, stream, x, cw, part);

  void* targs[] = {(void*)&part, (void*)&cb, (void*)&dw, (void*)&db,
                   (void*)&rw, (void*)&rb, (void*)&an,
                   (void*)&qacc, (void*)&s, (void*)&boxes,
                   (void*)&keysA, (void*)&keysB,
                   (void*)&ssc, (void*)&sboxes, (void*)&nz};
  hipLaunchCooperativeKernel((const void*)k_tail, dim3(8), dim3(1024), targs, 0, stream);

  hipLaunchKernelGGL(k_mask, dim3(108, 27), dim3(256), 0, stream, sboxes, mask, nz);
  hipLaunchKernelGGL(k_scan, dim3(1), dim3(256), 0, stream, mask, nz, ssc, sboxes, out);
}

// Round 4
// 323.838 us; speedup vs baseline: 1.0680x; 1.0680x over previous
//
#include <hip/hip_runtime.h>
#include <cstdint>

#define NPX 2304      // 48*48
#define MM 6912       // 3*2304
#define NW 108        // MM/64
#define TOPK 2000
#define NEGV -1000000000.0f
#define OBJ_THRF 0.3f
#define IOU_THRF 0.7f
#define IMGF 768.0f
#define KSPLIT 8      // conv k-splits: 32 ic per split

typedef unsigned long long u64;
typedef unsigned int u32;

__device__ __forceinline__ u64 shfl64(u64 v, int src) {
  int lo = __shfl((int)(v & 0xffffffffull), src, 64);
  int hi = __shfl((int)(v >> 32), src, 64);
  return ((u64)(u32)hi << 32) | (u32)lo;
}

// ---------------- weight transpose: wt[(ic*9+tap)][oc] = cw[oc][ic*9+tap] ---
__global__ __launch_bounds__(256) void k_wt(const float* __restrict__ cw,
                                            float* __restrict__ wt) {
  __shared__ float t[64][65];
  const int it0 = blockIdx.x * 64;   // grid.x = 36 (2304/64)
  const int oc0 = blockIdx.y * 64;   // grid.y = 4
  const int tx = threadIdx.x & 63;
  const int ty = threadIdx.x >> 6;
#pragma unroll
  for (int k = 0; k < 16; ++k) {
    int oc = ty + k * 4;
    t[oc][tx] = cw[(oc0 + oc) * 2304 + it0 + tx];  // coalesced read
  }
  __syncthreads();
#pragma unroll
  for (int k = 0; k < 16; ++k) {
    int it = ty + k * 4;
    wt[(it0 + it) * 256 + oc0 + tx] = t[tx][it];   // coalesced write
  }
}

// ---------------- conv 3x3, 256->256, fp32, scalar-weight form ----------------
// Round-0 geometry (grid 9x16x8, 16 oc/thread, s_load weights) — measured best
// at 65us — plus register-staged DOUBLE-BUFFER of the x tile (T14): chunk-1
// global loads are issued during chunk-0 compute and stay in flight across
// RAW s_barriers (no vmcnt(0) drain: loads are thread-private; barriers only
// need lgkmcnt for the ds_writes). Compute loop is instruction-for-instruction
// identical to round-0 -> bit-exact accumulation order.
__global__ __launch_bounds__(256) void k_conv(const float* __restrict__ x,
                                              const float* __restrict__ wt,
                                              float* __restrict__ part) {
  __shared__ float xs[16 * 8 * 52];  // 26,624 B
  const int tid = threadIdx.x;
  const int px = blockIdx.x * 256 + tid;
  const int oc0 = blockIdx.y * 16;
  const int ks = blockIdx.z;
  const int row = px / 48, col = px % 48;
  const int r0 = (blockIdx.x * 256) / 48;  // first row of this px-chunk
  const int rbase = row - r0;              // 0..5

  // prologue: register-stage chunk 0 (16 ic x 8 rows x 50 cols = 25*256 elems)
  float st[25];
#pragma unroll
  for (int k = 0; k < 25; ++k) {
    int e = tid + k * 256;
    int ic = e / 400, rem = e % 400;
    int r = rem / 50, c = rem % 50 - 1;
    int gr = r0 - 1 + r;
    float v = 0.f;
    if (c >= 0 && c < 48 && gr >= 0 && gr < 48)
      v = x[(ks * 32 + ic) * NPX + gr * 48 + c];
    st[k] = v;
  }

  float acc[16];
#pragma unroll
  for (int k = 0; k < 16; ++k) acc[k] = 0.f;

  for (int icc = 0; icc < 2; ++icc) {
    __builtin_amdgcn_sched_barrier(0);   // no ds_read of prev chunk sinks below
    __builtin_amdgcn_s_barrier();        // prev-chunk readers done (raw: no vm drain)
    __builtin_amdgcn_sched_barrier(0);   // no ds_write hoists above
#pragma unroll
    for (int k = 0; k < 25; ++k) {
      int e = tid + k * 256;
      int ic = e / 400, rem = e % 400;
      int r = rem / 50, c = rem % 50;    // == (col+1) of round-0's write
      xs[(ic * 8 + r) * 52 + c] = st[k];
    }
    if (icc == 0) {
      // prefetch chunk 1; latency hides under chunk-0 compute
#pragma unroll
      for (int k = 0; k < 25; ++k) {
        int e = tid + k * 256;
        int ic = e / 400, rem = e % 400;
        int r = rem / 50, c = rem % 50 - 1;
        int gr = r0 - 1 + r;
        float v = 0.f;
        if (c >= 0 && c < 48 && gr >= 0 && gr < 48)
          v = x[(ks * 32 + 16 + ic) * NPX + gr * 48 + c];
        st[k] = v;
      }
    }
    asm volatile("s_waitcnt lgkmcnt(0)" ::: "memory");  // ds_writes landed
    __builtin_amdgcn_s_barrier();
    __builtin_amdgcn_sched_barrier(0);   // no ds_read hoists above
    const int icg0 = ks * 32 + icc * 16;
    for (int ic = 0; ic < 16; ++ic) {
      float xv[9];
#pragma unroll
      for (int dr = 0; dr < 3; ++dr)
#pragma unroll
        for (int dc = 0; dc < 3; ++dc)
          xv[dr * 3 + dc] = xs[(ic * 8 + rbase + dr) * 52 + col + dc];
      const float* wrow = wt + (size_t)(icg0 + ic) * 9 * 256 + oc0;
#pragma unroll
      for (int t = 0; t < 9; ++t) {
        const float* wp = wrow + t * 256;  // wave-uniform -> s_load_dwordx16
#pragma unroll
        for (int k = 0; k < 16; ++k) acc[k] += xv[t] * wp[k];
      }
    }
  }
#pragma unroll
  for (int k = 0; k < 16; ++k)
    part[((size_t)ks * 256 + oc0 + k) * NPX + px] = acc[k];
}

// ---------------- heads, quarter-partial: grid (36 px-blks, 4 c-quarters) ---
__global__ __launch_bounds__(64) void k_dq(const float* __restrict__ part,
                                           const float* __restrict__ cb,
                                           const float* __restrict__ dw,
                                           const float* __restrict__ rw,
                                           float* __restrict__ qacc) {
  __shared__ float wl[64 * 16];   // this quarter's [ci][o]
  const int tid = threadIdx.x;    // pxl
  const int cq = blockIdx.y;
  const int px = blockIdx.x * 64 + tid;
  for (int e = tid; e < 960; e += 64) {
    int o = e % 15, ci = e / 15;
    int c = cq * 64 + ci;
    wl[ci * 16 + o] = (o < 3) ? dw[o * 256 + c] : rw[(o - 3) * 256 + c];
  }
  __syncthreads();
  float acc[15];
#pragma unroll
  for (int o = 0; o < 15; o++) acc[o] = 0.f;
#pragma unroll 4
  for (int ci = 0; ci < 64; ++ci) {
    int c = cq * 64 + ci;
    float v = cb[c];
#pragma unroll
    for (int kks = 0; kks < KSPLIT; ++kks)
      v += part[((size_t)kks * 256 + c) * NPX + px];
#pragma unroll
    for (int o = 0; o < 15; o++) acc[o] += v * wl[ci * 16 + o];
  }
#pragma unroll
  for (int o = 0; o < 15; o++)
    qacc[((size_t)cq * NPX + px) * 16 + o] = acc[o];
}

// ---------------- quarter reduce + anchor decode: grid 36, 64 thr ----------
__global__ __launch_bounds__(64) void k_dfin(const float* __restrict__ qacc,
                                             const float* __restrict__ db,
                                             const float* __restrict__ rb,
                                             const float* __restrict__ anch,
                                             float* __restrict__ s,
                                             float4* __restrict__ boxes) {
  const int tid = threadIdx.x;
  const int p = blockIdx.x * 64 + tid;
  float a[15];
#pragma unroll
  for (int o = 0; o < 15; o++)
    a[o] = qacc[((size_t)0 * NPX + p) * 16 + o] +
           qacc[((size_t)1 * NPX + p) * 16 + o] +
           qacc[((size_t)2 * NPX + p) * 16 + o] +
           qacc[((size_t)3 * NPX + p) * 16 + o];
  const float4* an4 = (const float4*)anch;
#pragma unroll
  for (int aa = 0; aa < 3; ++aa) {
    int m = aa * NPX + p;
    float logit = a[aa] + db[aa];
    float score = 1.f / (1.f + expf(-logit));
    float dxv = a[3 + 0 + aa] + rb[0 + aa];
    float dyv = a[3 + 3 + aa] + rb[3 + aa];
    float dwv = a[3 + 6 + aa] + rb[6 + aa];
    float dhv = a[3 + 9 + aa] + rb[9 + aa];
    float4 an = an4[m];
    float aw = an.z - an.x;
    float ah = an.w - an.y;
    float acx = an.y + aw * 0.5f;  // NOTE: intentionally swapped (reference quirk)
    float acy = an.x + ah * 0.5f;  // NOTE: intentionally swapped (reference quirk)
    float pxc = acx + dxv * aw;
    float pyc = acy + dyv * ah;
    float pw = aw * expf(dwv);
    float ph = ah * expf(dhv);
    float b0 = pxc - pw * 0.5f, b1 = pyc - ph * 0.5f;
    float b2 = pxc + pw * 0.5f, b3 = pyc + ph * 0.5f;
    b0 = fminf(fmaxf(b0, 0.f), IMGF);
    b1 = fminf(fmaxf(b1, 0.f), IMGF);
    b2 = fminf(fmaxf(b2, 0.f), IMGF);
    b3 = fminf(fmaxf(b3, 0.f), IMGF);
    float hts = b2 - b0, wds = b3 - b1;
    bool valid = (hts > 0.f) && (wds > 0.f) && (score > OBJ_THRF);
    s[m] = valid ? score : NEGV;
    boxes[m] = make_float4(b0, b1, b2, b3);
  }
}

// ---------------- sort phase 1: 8 blocks x 1024-elem bitonic runs ----------
__global__ __launch_bounds__(256) void k_sortA(const float* __restrict__ s,
                                               u64* __restrict__ keys) {
  __shared__ u64 lds[1024];
  const int tid = threadIdx.x;
  const int b = blockIdx.x;
  for (int v = tid; v < 1024; v += 256) {
    int i = b * 1024 + v;
    u64 p;
    if (i < MM) {
      u32 u = __float_as_uint(s[i]);
      u = u ^ (u32)(((int)u >> 31) | 0x80000000);
      p = ((u64)(~u) << 32) | (u32)i;
    } else {
      p = ~0ull;
    }
    lds[v] = p;
  }
  for (u32 kk = 2; kk <= 1024; kk <<= 1) {
    for (u32 j = kk >> 1; j > 0; j >>= 1) {
      __syncthreads();
#pragma unroll 2
      for (int t = tid; t < 512; t += 256) {
        int i = ((t & ~(j - 1)) << 1) | (t & (j - 1));
        int l = i | j;
        bool up = ((i & kk) == 0);
        u64 a = lds[i], c = lds[l];
        u64 mn = a < c ? a : c;
        u64 mx = a < c ? c : a;
        lds[i] = up ? mn : mx;
        lds[l] = up ? mx : mn;
      }
    }
  }
  __syncthreads();
  for (int v = tid; v < 1024; v += 256) keys[b * 1024 + v] = lds[v];
}

// ---------------- sort phase 2: merge-path rounds ----------------
__global__ __launch_bounds__(256) void k_merge(const u64* __restrict__ in,
                                               u64* __restrict__ outk, int L, int fin,
                                               const float* __restrict__ s,
                                               const float4* __restrict__ boxes,
                                               float* __restrict__ ssc,
                                               float4* __restrict__ sboxes) {
  const int i = blockIdx.x * 256 + threadIdx.x;  // 0..8191
  const int pair = i / (2 * L);
  const int r = i - pair * 2 * L;
  const u64* A = in + (size_t)pair * 2 * L;
  const u64* B = A + L;
  int lo = (r > L) ? (r - L) : 0;
  int hi = (r < L) ? r : L;
  while (lo < hi) {
    int mid = (lo + hi) >> 1;
    if (A[mid] < B[r - 1 - mid]) lo = mid + 1; else hi = mid;
  }
  int a = lo, bi = r - lo;
  u64 av = (a < L) ? A[a] : ~0ull;
  u64 bv = (bi < L) ? B[bi] : ~0ull;
  u64 o = (av < bv) ? av : bv;
  outk[i] = o;
  if (fin && i < MM) {
    int idx = (int)(u32)o;
    ssc[i] = s[idx];
    sboxes[i] = boxes[idx];
  }
}

// ---------------- zero-init nz bitmaps ----------------
__global__ __launch_bounds__(256) void k_zero(u64* __restrict__ nz) {
  int i = blockIdx.x * 256 + threadIdx.x;
  if (i < MM * 2) nz[i] = 0;
}

// ---------------- IOU suppression bit-matrix (transposed) ----------------
__global__ __launch_bounds__(256) void k_mask(const float4* __restrict__ sboxes,
                                              u64* __restrict__ mask_t,
                                              u64* __restrict__ nz) {
  __shared__ float4 rb_[64];
  const int rt = blockIdx.x;
  const int w = blockIdx.y * 4 + (threadIdx.x >> 6);
  const int lane = threadIdx.x & 63;
  if (threadIdx.x < 64) rb_[threadIdx.x] = sboxes[rt * 64 + threadIdx.x];
  __syncthreads();
  if (w < rt) return;
  float4 c = sboxes[w * 64 + lane];
  float areaC = (c.z - c.x) * (c.w - c.y);
  u64 myw = 0;
  for (int r = 0; r < 64; ++r) {
    float4 b = rb_[r];
    float iw = fmaxf(fminf(b.z, c.z) - fmaxf(b.x, c.x), 0.f);
    float ih = fmaxf(fminf(b.w, c.w) - fmaxf(b.y, c.y), 0.f);
    float inter = iw * ih;
    float areaB = (b.z - b.x) * (b.w - b.y);
    float un = fmaxf(areaB + areaC - inter, 1e-9f);
    bool bit = (inter / un) > IOU_THRF;
    u64 bal = __ballot(bit);
    if (lane == r) myw = bal;
  }
  mask_t[(size_t)w * MM + rt * 64 + lane] = myw;
  if (myw) atomicOr(&nz[(rt * 64 + lane) * 2 + (w >> 6)], 1ull << (w & 63));
}

// ---------------- serial NMS scan + output ----------------
__global__ __launch_bounds__(256) void k_scan(const u64* __restrict__ mask_t,
                                              const u64* __restrict__ nz,
                                              const float* __restrict__ ssc,
                                              const float4* __restrict__ sboxes,
                                              float* __restrict__ out) {
  __shared__ u64 remv[NW];
  __shared__ u64 keepw[NW];
  __shared__ int blist[64];
  __shared__ int nkS;
  __shared__ int kcntS;
  __shared__ int pref[NW];
  const int tid = threadIdx.x;
  if (tid < NW) { remv[tid] = 0; keepw[tid] = 0; }
  if (tid == 0) kcntS = 0;
  __syncthreads();

  for (int c = 0; c < NW; ++c) {
    if (tid < 64) {
      const int lane = tid;
      u64 dg = mask_t[(size_t)c * MM + c * 64 + lane];
      float sv = ssc[c * 64 + lane];
      u64 vb = __ballot(sv > OBJ_THRF);
      u64 w0 = remv[c];
      u64 cand = vb & ~w0;
      u64 above = (lane < 63) ? ~((2ull << lane) - 1ull) : 0ull;
      bool inC = ((cand >> lane) & 1ull) != 0;
      u64 conf = __ballot(inC && ((dg & above & cand) != 0ull));
      u64 kb;
      if (conf == 0ull) {
        kb = cand;
      } else {
        u64 w = w0;
        kb = 0;
        u64 rem = cand;
        while (rem) {
          int b = __ffsll(rem) - 1;
          kb |= (1ull << b);
          w |= shfl64(dg, b);
          rem = vb & ~w;
        }
      }
      int below = __popcll(kb & ((1ull << lane) - 1ull));
      if ((kb >> lane) & 1ull) blist[below] = lane;
      if (lane == 0) {
        keepw[c] = kb;
        nkS = __popcll(kb);
        kcntS += __popcll(kb);
      }
    }
    __syncthreads();
    int nk = nkS;
    if (tid < nk) {
      int row = c * 64 + blist[tid];
      u64 nz0 = nz[row * 2], nz1 = nz[row * 2 + 1];
      if (c < 64) {
        nz0 &= (c < 63) ? ~((2ull << c) - 1ull) : 0ull;
      } else {
        nz0 = 0;
        int cc = c - 64;
        nz1 &= ~((2ull << cc) - 1ull);
      }
      while (nz0) {
        int wv = __ffsll(nz0) - 1; nz0 &= nz0 - 1;
        atomicOr(&remv[wv], mask_t[(size_t)wv * MM + row]);
      }
      while (nz1) {
        int wv = __ffsll(nz1) - 1; nz1 &= nz1 - 1;
        atomicOr(&remv[wv + 64], mask_t[(size_t)(wv + 64) * MM + row]);
      }
    }
    __syncthreads();
    if (kcntS >= TOPK) break;
  }

  if (tid == 0) {
    int run = 0;
    for (int cc = 0; cc < NW; ++cc) { pref[cc] = run; run += __popcll(keepw[cc]); }
  }
  __syncthreads();
  for (int e = tid; e < TOPK * 5; e += 256) out[e] = (e < TOPK) ? -1.0f : 0.0f;
  __syncthreads();
  float4* ob = (float4*)(out + TOPK);
  for (int i = tid; i < MM; i += 256) {
    int cc = i >> 6, b = i & 63;
    u64 kb = keepw[cc];
    if ((kb >> b) & 1ull) {
      int rank = pref[cc] + __popcll(kb & ((1ull << b) - 1ull));
      if (rank < TOPK) {
        out[rank] = ssc[i];
        ob[rank] = sboxes[i];
      }
    }
  }
}

extern "C" void kernel_launch(void* const* d_in, const int* in_sizes, int n_in,
                              void* d_out, int out_size, void* d_ws, size_t ws_size,
                              hipStream_t stream) {
  const float* x  = (const float*)d_in[0];
  const float* cw = (const float*)d_in[1];
  const float* cb = (const float*)d_in[2];
  const float* dw = (const float*)d_in[3];
  const float* db = (const float*)d_in[4];
  const float* rw = (const float*)d_in[5];
  const float* rb = (const float*)d_in[6];
  const float* an = (const float*)d_in[7];
  char* ws = (char*)d_ws;
  // Time-phased aliasing of [0 .. 18.9MB):
  //   phase 1 (k_wt,k_conv,k_dq,k_dfin): part; qacc aliases wt region (wt dead
  //   after k_conv, qacc written by k_dq which launches after)
  //   phase 2 (k_zero..k_merge): keysA/B at [0..128KB), nz at 5,971,968
  //   phase 3 (k_mask,k_scan): mask at [0..5,971,968)
  float*  part   = (float*)(ws);                 // 18,874,368 B (KSPLIT*256*NPX*4)
  u64*    keysA  = (u64*)(ws);                   // 65,536 B
  u64*    keysB  = (u64*)(ws + 65536);           // 65,536 B
  u64*    mask   = (u64*)(ws);                   // 5,971,968 B
  u64*    nz     = (u64*)(ws + 5971968);         // 110,592 B
  float*  wt     = (float*)(ws + 18874368);      // 2,359,296 B
  float*  qacc   = (float*)(ws + 18874368);      // 589,824 B (aliases wt, ok)
  float*  s      = (float*)(ws + 21233664);      // 27,648 B
  float4* boxes  = (float4*)(ws + 21261312);     // 110,592 B
  float*  ssc    = (float*)(ws + 21371904);      // 27,648 B
  float4* sboxes = (float4*)(ws + 21399552);     // 110,592 B -> total 21,510,144 B
  float* out = (float*)d_out;

  hipLaunchKernelGGL(k_wt, dim3(36, 4), dim3(256), 0, stream, cw, wt);
  hipLaunchKernelGGL(k_conv, dim3(9, 16, KSPLIT), dim3(256), 0, stream, x, wt, part);
  hipLaunchKernelGGL(k_dq, dim3(36, 4), dim3(64), 0, stream, part, cb, dw, rw, qacc);
  hipLaunchKernelGGL(k_dfin, dim3(36), dim3(64), 0, stream, qacc, db, rb, an, s, boxes);
  hipLaunchKernelGGL(k_zero, dim3(54), dim3(256), 0, stream, nz);
  hipLaunchKernelGGL(k_sortA, dim3(8), dim3(256), 0, stream, s, keysA);
  hipLaunchKernelGGL(k_merge, dim3(32), dim3(256), 0, stream, keysA, keysB, 1024, 0, s, boxes, ssc, sboxes);
  hipLaunchKernelGGL(k_merge, dim3(32), dim3(256), 0, stream, keysB, keysA, 2048, 0, s, boxes, ssc, sboxes);
  hipLaunchKernelGGL(k_merge, dim3(32), dim3(256), 0, stream, keysA, keysB, 4096, 1, s, boxes, ssc, sboxes);
  hipLaunchKernelGGL(k_mask, dim3(108, 27), dim3(256), 0, stream, sboxes, mask, nz);
  hipLaunchKernelGGL(k_scan, dim3(1), dim3(256), 0, stream, mask, nz, ssc, sboxes, out);
}

// Round 6
// 269.635 us; speedup vs baseline: 1.2827x; 1.2010x over previous
//
#include <hip/hip_runtime.h>
#include <cstdint>

#define NPX 2304      // 48*48
#define MM 6912       // 3*2304
#define NW 108        // MM/64
#define TOPK 2000
#define NEGV -1000000000.0f
#define OBJ_THRF 0.3f
#define IOU_THRF 0.7f
#define IMGF 768.0f
#define KSPLIT 8      // conv k-splits: 32 ic per split

typedef unsigned long long u64;
typedef unsigned int u32;

__device__ __forceinline__ u64 shfl64(u64 v, int src) {
  int lo = __shfl((int)(v & 0xffffffffull), src, 64);
  int hi = __shfl((int)(v >> 32), src, 64);
  return ((u64)(u32)hi << 32) | (u32)lo;
}

__device__ __forceinline__ void gl_lds(const float* g, float* l) {
  __builtin_amdgcn_global_load_lds(
      (const __attribute__((address_space(1))) void*)g,
      (__attribute__((address_space(3))) void*)l, 4, 0, 0);
}

// ---------------- weight transpose: wt[(ic*9+tap)][oc] = cw[oc][ic*9+tap] ---
__global__ __launch_bounds__(256) void k_wt(const float* __restrict__ cw,
                                            float* __restrict__ wt) {
  __shared__ float t[64][65];
  const int it0 = blockIdx.x * 64;   // grid.x = 36 (2304/64)
  const int oc0 = blockIdx.y * 64;   // grid.y = 4
  const int tx = threadIdx.x & 63;
  const int ty = threadIdx.x >> 6;
#pragma unroll
  for (int k = 0; k < 16; ++k) {
    int oc = ty + k * 4;
    t[oc][tx] = cw[(oc0 + oc) * 2304 + it0 + tx];  // coalesced read
  }
  __syncthreads();
#pragma unroll
  for (int k = 0; k < 16; ++k) {
    int it = ty + k * 4;
    wt[(it0 + it) * 256 + oc0 + tx] = t[tx][it];   // coalesced write
  }
}

// ---------------- conv 3x3, 256->256, fp32, scalar-weight form ----------------
// Round-0 geometry (grid 9x16x8, 16 oc/thread, s_load weights; measured best)
// + global_load_lds double-buffered staging: NO staging VGPRs (r4's 88-VGPR
// mistake), halo handled by pre-zeroed LDS + EXEC-masked glld, LDS layout
// [16][8][50] linear so HW base+lane*4 matches. Chunk-1 loads issue before
// chunk-0 compute and complete under its ~4900 FMA cycles. Compute loop is
// instruction-for-instruction round-0 -> bit-exact accumulation order.
__global__ __launch_bounds__(256) void k_conv(const float* __restrict__ x,
                                              const float* __restrict__ wt,
                                              float* __restrict__ part) {
  __shared__ float xs[2][16 * 8 * 50];  // 2 x 25,600 B = 51,200 B
  const int tid = threadIdx.x;
  const int px = blockIdx.x * 256 + tid;
  const int oc0 = blockIdx.y * 16;
  const int ks = blockIdx.z;
  const int row = px / 48, col = px % 48;
  const int r0 = (blockIdx.x * 256) / 48;  // first row of this px-chunk
  const int rbase = row - r0;              // 0..5

  // zero both buffers once: halo slots stay zero forever (both chunks share
  // the same halo geometry); glld only overwrites valid lanes' slots.
  {
    float4 z4 = make_float4(0.f, 0.f, 0.f, 0.f);
    float4* p4 = (float4*)&xs[0][0];
    for (int e = tid; e < 2 * 6400 / 4; e += 256) p4[e] = z4;
  }
  __syncthreads();

  float acc[16];
#pragma unroll
  for (int k = 0; k < 16; ++k) acc[k] = 0.f;

  // ---- stage chunk 0 ----
#pragma unroll
  for (int k = 0; k < 25; ++k) {
    int e = tid + k * 256;
    int ic = e / 400, rem = e % 400;
    int r = rem / 50, c = rem % 50;
    int gr = r0 - 1 + r, gc = c - 1;
    if (gc >= 0 && gc < 48 && gr >= 0 && gr < 48)
      gl_lds(x + (size_t)(ks * 32 + ic) * NPX + gr * 48 + gc,
             &xs[0][e & ~63]);
  }
  __syncthreads();   // vmcnt drain (prologue only) + barrier

  // ---- issue stage chunk 1 (stays in flight under chunk-0 compute) ----
#pragma unroll
  for (int k = 0; k < 25; ++k) {
    int e = tid + k * 256;
    int ic = e / 400, rem = e % 400;
    int r = rem / 50, c = rem % 50;
    int gr = r0 - 1 + r, gc = c - 1;
    if (gc >= 0 && gc < 48 && gr >= 0 && gr < 48)
      gl_lds(x + (size_t)(ks * 32 + 16 + ic) * NPX + gr * 48 + gc,
             &xs[1][e & ~63]);
  }

  // ---- compute chunk 0 (ic 0..15 of this ksplit) ----
  for (int icc = 0; icc < 2; ++icc) {
    const float* xb = &xs[icc][0];
    const int icg0 = ks * 32 + icc * 16;
    for (int ic = 0; ic < 16; ++ic) {
      float xv[9];
#pragma unroll
      for (int dr = 0; dr < 3; ++dr)
#pragma unroll
        for (int dc = 0; dc < 3; ++dc)
          xv[dr * 3 + dc] = xb[(ic * 8 + rbase + dr) * 50 + col + dc];
      const float* wrow = wt + (size_t)(icg0 + ic) * 9 * 256 + oc0;
#pragma unroll
      for (int t = 0; t < 9; ++t) {
        const float* wp = wrow + t * 256;  // wave-uniform -> s_load_dwordx16
#pragma unroll
        for (int k = 0; k < 16; ++k) acc[k] += xv[t] * wp[k];
      }
    }
    if (icc == 0) __syncthreads();  // chunk-1 loads landed (hidden) + barrier
  }
#pragma unroll
  for (int k = 0; k < 16; ++k)
    part[((size_t)ks * 256 + oc0 + k) * NPX + px] = acc[k];
}

// ---------------- ksplit reduce: inter[c][px] = cb[c] + sum_ks part --------
// Identical left-assoc chain ((cb+p0)+p1)+...+p7 as round-0's k_decode ->
// bit-exact. Massively parallel (2304 blocks) vs k_dq's 144 latency-bound
// waves doing 8-deep scattered reads.
__global__ __launch_bounds__(256) void k_red(const float* __restrict__ part,
                                             const float* __restrict__ cb,
                                             float* __restrict__ inter) {
  const int px = blockIdx.x * 256 + threadIdx.x;  // grid.x = 9
  const int c  = blockIdx.y;                      // grid.y = 256
  float v = cb[c];
#pragma unroll
  for (int ks = 0; ks < KSPLIT; ++ks)
    v += part[((size_t)ks * 256 + c) * NPX + px];
  inter[(size_t)c * NPX + px] = v;
}

// ---------------- heads, quarter-partial: grid (36 px-blks, 4 c-quarters) ---
__global__ __launch_bounds__(64) void k_dq(const float* __restrict__ inter,
                                           const float* __restrict__ dw,
                                           const float* __restrict__ rw,
                                           float* __restrict__ qacc) {
  __shared__ float wl[64 * 16];   // this quarter's [ci][o]
  const int tid = threadIdx.x;    // pxl
  const int cq = blockIdx.y;
  const int px = blockIdx.x * 64 + tid;
  for (int e = tid; e < 960; e += 64) {
    int o = e % 15, ci = e / 15;
    int c = cq * 64 + ci;
    wl[ci * 16 + o] = (o < 3) ? dw[o * 256 + c] : rw[(o - 3) * 256 + c];
  }
  __syncthreads();
  float acc[15];
#pragma unroll
  for (int o = 0; o < 15; o++) acc[o] = 0.f;
#pragma unroll 4
  for (int ci = 0; ci < 64; ++ci) {
    int c = cq * 64 + ci;
    float v = inter[(size_t)c * NPX + px];
#pragma unroll
    for (int o = 0; o < 15; o++) acc[o] += v * wl[ci * 16 + o];
  }
#pragma unroll
  for (int o = 0; o < 15; o++)
    qacc[((size_t)cq * NPX + px) * 16 + o] = acc[o];
}

// ---------------- quarter reduce + anchor decode: grid 36, 64 thr ----------
__global__ __launch_bounds__(64) void k_dfin(const float* __restrict__ qacc,
                                             const float* __restrict__ db,
                                             const float* __restrict__ rb,
                                             const float* __restrict__ anch,
                                             float* __restrict__ s,
                                             float4* __restrict__ boxes) {
  const int tid = threadIdx.x;
  const int p = blockIdx.x * 64 + tid;
  float a[15];
#pragma unroll
  for (int o = 0; o < 15; o++)
    a[o] = qacc[((size_t)0 * NPX + p) * 16 + o] +
           qacc[((size_t)1 * NPX + p) * 16 + o] +
           qacc[((size_t)2 * NPX + p) * 16 + o] +
           qacc[((size_t)3 * NPX + p) * 16 + o];
  const float4* an4 = (const float4*)anch;
#pragma unroll
  for (int aa = 0; aa < 3; ++aa) {
    int m = aa * NPX + p;
    float logit = a[aa] + db[aa];
    float score = 1.f / (1.f + expf(-logit));
    float dxv = a[3 + 0 + aa] + rb[0 + aa];
    float dyv = a[3 + 3 + aa] + rb[3 + aa];
    float dwv = a[3 + 6 + aa] + rb[6 + aa];
    float dhv = a[3 + 9 + aa] + rb[9 + aa];
    float4 an = an4[m];
    float aw = an.z - an.x;
    float ah = an.w - an.y;
    float acx = an.y + aw * 0.5f;  // NOTE: intentionally swapped (reference quirk)
    float acy = an.x + ah * 0.5f;  // NOTE: intentionally swapped (reference quirk)
    float pxc = acx + dxv * aw;
    float pyc = acy + dyv * ah;
    float pw = aw * expf(dwv);
    float ph = ah * expf(dhv);
    float b0 = pxc - pw * 0.5f, b1 = pyc - ph * 0.5f;
    float b2 = pxc + pw * 0.5f, b3 = pyc + ph * 0.5f;
    b0 = fminf(fmaxf(b0, 0.f), IMGF);
    b1 = fminf(fmaxf(b1, 0.f), IMGF);
    b2 = fminf(fmaxf(b2, 0.f), IMGF);
    b3 = fminf(fmaxf(b3, 0.f), IMGF);
    float hts = b2 - b0, wds = b3 - b1;
    bool valid = (hts > 0.f) && (wds > 0.f) && (score > OBJ_THRF);
    s[m] = valid ? score : NEGV;
    boxes[m] = make_float4(b0, b1, b2, b3);
  }
}

// ---------------- sort phase 1: 8 blocks x 1024-elem bitonic runs ----------
// also zero-inits the nz bitmaps (folded k_zero: -1 launch)
__global__ __launch_bounds__(256) void k_sortA(const float* __restrict__ s,
                                               u64* __restrict__ keys,
                                               u64* __restrict__ nz) {
  __shared__ u64 lds[1024];
  const int tid = threadIdx.x;
  const int b = blockIdx.x;
  for (int i = b * 256 + tid; i < MM * 2; i += 8 * 256) nz[i] = 0;
  for (int v = tid; v < 1024; v += 256) {
    int i = b * 1024 + v;
    u64 p;
    if (i < MM) {
      u32 u = __float_as_uint(s[i]);
      u = u ^ (u32)(((int)u >> 31) | 0x80000000);
      p = ((u64)(~u) << 32) | (u32)i;
    } else {
      p = ~0ull;
    }
    lds[v] = p;
  }
  for (u32 kk = 2; kk <= 1024; kk <<= 1) {
    for (u32 j = kk >> 1; j > 0; j >>= 1) {
      __syncthreads();
#pragma unroll 2
      for (int t = tid; t < 512; t += 256) {
        int i = ((t & ~(j - 1)) << 1) | (t & (j - 1));
        int l = i | j;
        bool up = ((i & kk) == 0);
        u64 a = lds[i], c = lds[l];
        u64 mn = a < c ? a : c;
        u64 mx = a < c ? c : a;
        lds[i] = up ? mn : mx;
        lds[l] = up ? mx : mn;
      }
    }
  }
  __syncthreads();
  for (int v = tid; v < 1024; v += 256) keys[b * 1024 + v] = lds[v];
}

// ---------------- sort phase 2: merge-path rounds ----------------
__global__ __launch_bounds__(256) void k_merge(const u64* __restrict__ in,
                                               u64* __restrict__ outk, int L, int fin,
                                               const float* __restrict__ s,
                                               const float4* __restrict__ boxes,
                                               float* __restrict__ ssc,
                                               float4* __restrict__ sboxes) {
  const int i = blockIdx.x * 256 + threadIdx.x;  // 0..8191
  const int pair = i / (2 * L);
  const int r = i - pair * 2 * L;
  const u64* A = in + (size_t)pair * 2 * L;
  const u64* B = A + L;
  int lo = (r > L) ? (r - L) : 0;
  int hi = (r < L) ? r : L;
  while (lo < hi) {
    int mid = (lo + hi) >> 1;
    if (A[mid] < B[r - 1 - mid]) lo = mid + 1; else hi = mid;
  }
  int a = lo, bi = r - lo;
  u64 av = (a < L) ? A[a] : ~0ull;
  u64 bv = (bi < L) ? B[bi] : ~0ull;
  u64 o = (av < bv) ? av : bv;
  outk[i] = o;
  if (fin && i < MM) {
    int idx = (int)(u32)o;
    ssc[i] = s[idx];
    sboxes[i] = boxes[idx];
  }
}

// ---------------- IOU suppression bit-matrix (transposed) ----------------
__global__ __launch_bounds__(256) void k_mask(const float4* __restrict__ sboxes,
                                              u64* __restrict__ mask_t,
                                              u64* __restrict__ nz) {
  __shared__ float4 rb_[64];
  const int rt = blockIdx.x;
  const int w = blockIdx.y * 4 + (threadIdx.x >> 6);
  const int lane = threadIdx.x & 63;
  if (threadIdx.x < 64) rb_[threadIdx.x] = sboxes[rt * 64 + threadIdx.x];
  __syncthreads();
  if (w < rt) return;
  float4 c = sboxes[w * 64 + lane];
  float areaC = (c.z - c.x) * (c.w - c.y);
  u64 myw = 0;
  for (int r = 0; r < 64; ++r) {
    float4 b = rb_[r];
    float iw = fmaxf(fminf(b.z, c.z) - fmaxf(b.x, c.x), 0.f);
    float ih = fmaxf(fminf(b.w, c.w) - fmaxf(b.y, c.y), 0.f);
    float inter = iw * ih;
    float areaB = (b.z - b.x) * (b.w - b.y);
    float un = fmaxf(areaB + areaC - inter, 1e-9f);
    bool bit = (inter / un) > IOU_THRF;
    u64 bal = __ballot(bit);
    if (lane == r) myw = bal;
  }
  mask_t[(size_t)w * MM + rt * 64 + lane] = myw;
  if (myw) atomicOr(&nz[(rt * 64 + lane) * 2 + (w >> 6)], 1ull << (w & 63));
}

// ---------------- serial NMS scan + output ----------------
// Diagonal mask rows + sorted scores prefetched into LDS (83 KB): removes the
// serial global-latency from each of the ~NW chunk iterations' phase A.
__global__ __launch_bounds__(256) void k_scan(const u64* __restrict__ mask_t,
                                              const u64* __restrict__ nz,
                                              const float* __restrict__ ssc,
                                              const float4* __restrict__ sboxes,
                                              float* __restrict__ out) {
  __shared__ u64 diagL[NW * 64];   // 55,296 B
  __shared__ float sscL[MM];       // 27,648 B
  __shared__ u64 remv[NW];
  __shared__ u64 keepw[NW];
  __shared__ int blist[64];
  __shared__ int nkS;
  __shared__ int kcntS;
  __shared__ int pref[NW];
  const int tid = threadIdx.x;
  for (int e = tid; e < NW * 64; e += 256)
    diagL[e] = mask_t[(size_t)(e >> 6) * MM + (e >> 6) * 64 + (e & 63)];
  for (int e = tid; e < MM; e += 256) sscL[e] = ssc[e];
  if (tid < NW) { remv[tid] = 0; keepw[tid] = 0; }
  if (tid == 0) kcntS = 0;
  __syncthreads();

  for (int c = 0; c < NW; ++c) {
    if (tid < 64) {
      const int lane = tid;
      u64 dg = diagL[c * 64 + lane];
      float sv = sscL[c * 64 + lane];
      u64 vb = __ballot(sv > OBJ_THRF);
      u64 w0 = remv[c];
      u64 cand = vb & ~w0;
      u64 above = (lane < 63) ? ~((2ull << lane) - 1ull) : 0ull;
      bool inC = ((cand >> lane) & 1ull) != 0;
      u64 conf = __ballot(inC && ((dg & above & cand) != 0ull));
      u64 kb;
      if (conf == 0ull) {
        kb = cand;
      } else {
        u64 w = w0;
        kb = 0;
        u64 rem = cand;
        while (rem) {
          int b = __ffsll(rem) - 1;
          kb |= (1ull << b);
          w |= shfl64(dg, b);
          rem = vb & ~w;
        }
      }
      int below = __popcll(kb & ((1ull << lane) - 1ull));
      if ((kb >> lane) & 1ull) blist[below] = lane;
      if (lane == 0) {
        keepw[c] = kb;
        nkS = __popcll(kb);
        kcntS += __popcll(kb);
      }
    }
    __syncthreads();
    int nk = nkS;
    if (tid < nk) {
      int row = c * 64 + blist[tid];
      u64 nz0 = nz[row * 2], nz1 = nz[row * 2 + 1];
      if (c < 64) {
        nz0 &= (c < 63) ? ~((2ull << c) - 1ull) : 0ull;
      } else {
        nz0 = 0;
        int cc = c - 64;
        nz1 &= ~((2ull << cc) - 1ull);
      }
      while (nz0) {
        int wv = __ffsll(nz0) - 1; nz0 &= nz0 - 1;
        atomicOr(&remv[wv], mask_t[(size_t)wv * MM + row]);
      }
      while (nz1) {
        int wv = __ffsll(nz1) - 1; nz1 &= nz1 - 1;
        atomicOr(&remv[wv + 64], mask_t[(size_t)(wv + 64) * MM + row]);
      }
    }
    __syncthreads();
    if (kcntS >= TOPK) break;
  }

  if (tid == 0) {
    int run = 0;
    for (int cc = 0; cc < NW; ++cc) { pref[cc] = run; run += __popcll(keepw[cc]); }
  }
  __syncthreads();
  for (int e = tid; e < TOPK * 5; e += 256) out[e] = (e < TOPK) ? -1.0f : 0.0f;
  __syncthreads();
  float4* ob = (float4*)(out + TOPK);
  for (int i = tid; i < MM; i += 256) {
    int cc = i >> 6, b = i & 63;
    u64 kb = keepw[cc];
    if ((kb >> b) & 1ull) {
      int rank = pref[cc] + __popcll(kb & ((1ull << b) - 1ull));
      if (rank < TOPK) {
        out[rank] = sscL[i];
        ob[rank] = sboxes[i];
      }
    }
  }
}

extern "C" void kernel_launch(void* const* d_in, const int* in_sizes, int n_in,
                              void* d_out, int out_size, void* d_ws, size_t ws_size,
                              hipStream_t stream) {
  const float* x  = (const float*)d_in[0];
  const float* cw = (const float*)d_in[1];
  const float* cb = (const float*)d_in[2];
  const float* dw = (const float*)d_in[3];
  const float* db = (const float*)d_in[4];
  const float* rw = (const float*)d_in[5];
  const float* rb = (const float*)d_in[6];
  const float* an = (const float*)d_in[7];
  char* ws = (char*)d_ws;
  // Time-phased aliasing (total 21,510,144 B, same footprint as r0):
  //   k_wt,k_conv:            wt  [18.87M..21.23M), part [0..18.87M)
  //   k_red:                  reads part, writes inter over dead wt
  //   k_dq,k_dfin:            qacc [0..589,824) over dead part; reads inter
  //   k_sortA..k_merge:       keysA/B [0..128K) over dead qacc; nz at 5.97M
  //   k_mask,k_scan:          mask [0..5.97M) over dead keys
  float*  part   = (float*)(ws);                 // 18,874,368 B
  float*  qacc   = (float*)(ws);                 // 589,824 B (part dead)
  u64*    keysA  = (u64*)(ws);                   // 65,536 B (qacc dead)
  u64*    keysB  = (u64*)(ws + 65536);           // 65,536 B
  u64*    mask   = (u64*)(ws);                   // 5,971,968 B (keys dead)
  u64*    nz     = (u64*)(ws + 5971968);         // 110,592 B
  float*  wt     = (float*)(ws + 18874368);      // 2,359,296 B
  float*  inter  = (float*)(ws + 18874368);      // 2,359,296 B (wt dead)
  float*  s      = (float*)(ws + 21233664);      // 27,648 B
  float4* boxes  = (float4*)(ws + 21261312);     // 110,592 B
  float*  ssc    = (float*)(ws + 21371904);      // 27,648 B
  float4* sboxes = (float4*)(ws + 21399552);     // 110,592 B -> total 21,510,144 B
  float* out = (float*)d_out;

  hipLaunchKernelGGL(k_wt, dim3(36, 4), dim3(256), 0, stream, cw, wt);
  hipLaunchKernelGGL(k_conv, dim3(9, 16, KSPLIT), dim3(256), 0, stream, x, wt, part);
  hipLaunchKernelGGL(k_red, dim3(9, 256), dim3(256), 0, stream, part, cb, inter);
  hipLaunchKernelGGL(k_dq, dim3(36, 4), dim3(64), 0, stream, inter, dw, rw, qacc);
  hipLaunchKernelGGL(k_dfin, dim3(36), dim3(64), 0, stream, qacc, db, rb, an, s, boxes);
  hipLaunchKernelGGL(k_sortA, dim3(8), dim3(256), 0, stream, s, keysA, nz);
  hipLaunchKernelGGL(k_merge, dim3(32), dim3(256), 0, stream, keysA, keysB, 1024, 0, s, boxes, ssc, sboxes);
  hipLaunchKernelGGL(k_merge, dim3(32), dim3(256), 0, stream, keysB, keysA, 2048, 0, s, boxes, ssc, sboxes);
  hipLaunchKernelGGL(k_merge, dim3(32), dim3(256), 0, stream, keysA, keysB, 4096, 1, s, boxes, ssc, sboxes);
  hipLaunchKernelGGL(k_mask, dim3(108, 27), dim3(256), 0, stream, sboxes, mask, nz);
  hipLaunchKernelGGL(k_scan, dim3(1), dim3(256), 0, stream, mask, nz, ssc, sboxes, out);
}